// Round 1
// baseline (235.082 us; speedup 1.0000x reference)
//
#include <hip/hip_runtime.h>
#include <cmath>

// BertEmbeddings: B=8, S=2048, H=768. fp32 in/out.
// History:
//  R0 wave-per-token, sinf:            kernel 77us (VALU 25%, VGPR 116)
//  R1 launch_bounds(256,6):            SPILL disaster (WRITE 49->246 MB)
//  R3 __sinf + nt-store + (256,4):     kernel ~58us
//  R4 + LDS params + (256,5):          kernel ~54us
//  R6 chunk-per-thread (192thr/token): kernel 76us — reverted.
//  R7 readfirstlane-scalarized ids + all-15-gathers-flattened: dur 231.2us
//     (= 3x59us harness fills + ~53us kernel).
// R8 (this round): kernel modeled at ~3x above BW/VALU floor (~16us) =>
//     latency-bound theory. Two tokens per wave, software-pipelined:
//     T1's 15 gathers issue before T0's reduce/normalize/store so their
//     HBM latency hides under T0's tail. Token concurrency/SIMD 5->8
//     (4 waves x 2 tokens @ (256,4), VGPR cap 128 holds the 60-VGPR
//     gather set). LDS staging + id broadcasts amortized 2x. Butterfly
//     __shfl_xor reduction (no final broadcast step).
static constexpr int B_ = 8;
static constexpr int S_ = 2048;
static constexpr int H_ = 768;            // 192 float4 chunks per row
static constexpr int TOKENS = B_ * S_;    // 16384
static constexpr float LN_EPS = 1e-12f;

typedef float nfloat4 __attribute__((ext_vector_type(4)));

__device__ __forceinline__ float rfl_f32(float x) {
    return __uint_as_float(__builtin_amdgcn_readfirstlane(__float_as_uint(x)));
}

// Consume one token's 15 gathered float4 chunks -> embedding vals + sum/sumsq.
// Fully inlined; all array indices compile-time after unroll (no scratch).
__device__ __forceinline__ void consume_token(
    const float4 g[15], float atau, float dtau,
    float aw0, float ab0, float dw0, float db0, int lane,
    const float4* awv, const float4* abv, const float4* dwv, const float4* dbv,
    float vals[12], float& ssum, float& ssq)
{
#pragma unroll
    for (int c = 0; c < 3; ++c) {
        const int h4 = lane + (c << 6);        // 0..191
        const float4 aw = awv[h4];
        const float4 ab = abv[h4];
        const float4 dw = dwv[h4];
        const float4 db = dbv[h4];

        float av0 = __sinf(atau * aw.x + ab.x);
        float av1 = __sinf(atau * aw.y + ab.y);
        float av2 = __sinf(atau * aw.z + ab.z);
        float av3 = __sinf(atau * aw.w + ab.w);
        float dv0 = __sinf(dtau * dw.x + db.x);
        float dv1 = __sinf(dtau * dw.y + db.y);
        float dv2 = __sinf(dtau * dw.z + db.z);
        float dv3 = __sinf(dtau * dw.w + db.w);
        if (h4 == (H_ / 4 - 1)) {              // h = 767: linear branch of time2vec
            av3 = atau * aw0 + ab0;
            dv3 = dtau * dw0 + db0;
        }

        const float4 we = g[c * 5 + 0];
        const float4 me = g[c * 5 + 1];
        const float4 se = g[c * 5 + 2];
        const float4 ne = g[c * 5 + 3];
        const float4 pe = g[c * 5 + 4];

        const float e0 = we.x + me.x + se.x + ne.x + pe.x + av0 + dv0;
        const float e1 = we.y + me.y + se.y + ne.y + pe.y + av1 + dv1;
        const float e2 = we.z + me.z + se.z + ne.z + pe.z + av2 + dv2;
        const float e3 = we.w + me.w + se.w + ne.w + pe.w + av3 + dv3;

        vals[c * 4 + 0] = e0;
        vals[c * 4 + 1] = e1;
        vals[c * 4 + 2] = e2;
        vals[c * 4 + 3] = e3;
        ssum += e0 + e1 + e2 + e3;
        ssq  += e0 * e0 + e1 * e1 + e2 * e2 + e3 * e3;
    }
}

// 64-lane butterfly reduce of two independent chains (latencies overlap);
// every lane ends with the wave total — no broadcast step needed.
__device__ __forceinline__ void wave_reduce2(float& s, float& q) {
#pragma unroll
    for (int m = 32; m; m >>= 1) {
        s += __shfl_xor(s, m);
        q += __shfl_xor(q, m);
    }
}

__device__ __forceinline__ void apply_store(
    const float vals[12], float mu, float rstd, int lane,
    const float4* gv, const float4* bv, nfloat4* orow)
{
#pragma unroll
    for (int c = 0; c < 3; ++c) {
        const int h4 = lane + (c << 6);
        const float4 g  = gv[h4];
        const float4 bt = bv[h4];
        nfloat4 o;
        o.x = (vals[c * 4 + 0] - mu) * rstd * g.x + bt.x;
        o.y = (vals[c * 4 + 1] - mu) * rstd * g.y + bt.y;
        o.z = (vals[c * 4 + 2] - mu) * rstd * g.z + bt.z;
        o.w = (vals[c * 4 + 3] - mu) * rstd * g.w + bt.w;
        __builtin_nontemporal_store(o, &orow[h4]);
    }
}

__global__ __launch_bounds__(256, 4) void bert_emb_kernel(
    const int* __restrict__ word_ids,
    const int* __restrict__ modal_ids,
    const int* __restrict__ seg_ids,
    const int* __restrict__ npi_ids,
    const int* __restrict__ posi_ids,
    const float* __restrict__ age_tau,
    const float* __restrict__ delay_tau,
    const float* __restrict__ word_table,
    const float* __restrict__ modal_table,
    const float* __restrict__ seg_table,
    const float* __restrict__ npi_table,
    const float* __restrict__ posi_table,
    const float* __restrict__ age_w,      // [767]
    const float* __restrict__ age_b,      // [767]
    const float* __restrict__ age_w0,     // [1]
    const float* __restrict__ age_b0,     // [1]
    const float* __restrict__ delay_w,    // [767]
    const float* __restrict__ delay_b,    // [767]
    const float* __restrict__ delay_w0,   // [1]
    const float* __restrict__ delay_b0,   // [1]
    const float* __restrict__ ln_gamma,   // [768]
    const float* __restrict__ ln_beta,    // [768]
    float* __restrict__ out)
{
    __shared__ __align__(16) float s_aw[H_];
    __shared__ __align__(16) float s_ab[H_];
    __shared__ __align__(16) float s_dw[H_];
    __shared__ __align__(16) float s_db[H_];
    __shared__ __align__(16) float s_g [H_];
    __shared__ __align__(16) float s_bt[H_];

    // Cooperative stage of token-invariant vectors (pad element 767 with 0).
    // Amortized over 8 tokens/block now (was 4).
    for (int i = threadIdx.x; i < H_; i += 256) {
        const bool in = (i < H_ - 1);
        s_aw[i] = in ? age_w[i]   : 0.0f;
        s_ab[i] = in ? age_b[i]   : 0.0f;
        s_dw[i] = in ? delay_w[i] : 0.0f;
        s_db[i] = in ? delay_b[i] : 0.0f;
        s_g [i] = ln_gamma[i];
        s_bt[i] = ln_beta[i];
    }
    __syncthreads();

    const int wave = threadIdx.x >> 6;         // 0..3
    const int lane = threadIdx.x & 63;         // 0..63
    const int t0 = (blockIdx.x << 3) + (wave << 1);  // grid = TOKENS/8 exactly
    const int t1 = t0 + 1;

    // Wave-uniform scalars for BOTH tokens, forced into SGPRs.
    const int wid0 = __builtin_amdgcn_readfirstlane(word_ids[t0]);
    const int mid0 = __builtin_amdgcn_readfirstlane(modal_ids[t0]);
    const int sid0 = __builtin_amdgcn_readfirstlane(seg_ids[t0]);
    const int nid0 = __builtin_amdgcn_readfirstlane(npi_ids[t0]);
    const int pid0 = __builtin_amdgcn_readfirstlane(posi_ids[t0]);
    const int wid1 = __builtin_amdgcn_readfirstlane(word_ids[t1]);
    const int mid1 = __builtin_amdgcn_readfirstlane(modal_ids[t1]);
    const int sid1 = __builtin_amdgcn_readfirstlane(seg_ids[t1]);
    const int nid1 = __builtin_amdgcn_readfirstlane(npi_ids[t1]);
    const int pid1 = __builtin_amdgcn_readfirstlane(posi_ids[t1]);
    const float atau0 = rfl_f32(age_tau[t0]);
    const float dtau0 = rfl_f32(delay_tau[t0]);
    const float atau1 = rfl_f32(age_tau[t1]);
    const float dtau1 = rfl_f32(delay_tau[t1]);
    const float aw0 = age_w0[0], ab0 = age_b0[0];
    const float dw0 = delay_w0[0], db0 = delay_b0[0];

    const float4* wrow0 = reinterpret_cast<const float4*>(word_table  + (size_t)wid0 * H_);
    const float4* mrow0 = reinterpret_cast<const float4*>(modal_table + (size_t)mid0 * H_);
    const float4* srow0 = reinterpret_cast<const float4*>(seg_table   + (size_t)sid0 * H_);
    const float4* nrow0 = reinterpret_cast<const float4*>(npi_table   + (size_t)nid0 * H_);
    const float4* prow0 = reinterpret_cast<const float4*>(posi_table  + (size_t)pid0 * H_);
    const float4* wrow1 = reinterpret_cast<const float4*>(word_table  + (size_t)wid1 * H_);
    const float4* mrow1 = reinterpret_cast<const float4*>(modal_table + (size_t)mid1 * H_);
    const float4* srow1 = reinterpret_cast<const float4*>(seg_table   + (size_t)sid1 * H_);
    const float4* nrow1 = reinterpret_cast<const float4*>(npi_table   + (size_t)nid1 * H_);
    const float4* prow1 = reinterpret_cast<const float4*>(posi_table  + (size_t)pid1 * H_);

    const float4* awv = reinterpret_cast<const float4*>(s_aw);
    const float4* abv = reinterpret_cast<const float4*>(s_ab);
    const float4* dwv = reinterpret_cast<const float4*>(s_dw);
    const float4* dbv = reinterpret_cast<const float4*>(s_db);
    const float4* gv  = reinterpret_cast<const float4*>(s_g);
    const float4* bv  = reinterpret_cast<const float4*>(s_bt);

    // ---- Token 0: issue ALL 15 gathers (one vmcnt group, max MLP) ----
    float4 g0[15];
#pragma unroll
    for (int c = 0; c < 3; ++c) {
        const int o = lane + (c << 6);
        g0[c * 5 + 0] = wrow0[o];
        g0[c * 5 + 1] = mrow0[o];
        g0[c * 5 + 2] = srow0[o];
        g0[c * 5 + 3] = nrow0[o];
        g0[c * 5 + 4] = prow0[o];
    }

    float vals0[12];
    float s0 = 0.0f, q0 = 0.0f;
    consume_token(g0, atau0, dtau0, aw0, ab0, dw0, db0, lane,
                  awv, abv, dwv, dbv, vals0, s0, q0);

    // ---- Token 1: issue its 15 gathers NOW, before T0's reduction /
    // normalize / store — their ~900cy HBM latency hides under T0's tail.
    // (g0 registers are dead here, so peak live gather set stays ~60 VGPR.)
    float4 g1[15];
#pragma unroll
    for (int c = 0; c < 3; ++c) {
        const int o = lane + (c << 6);
        g1[c * 5 + 0] = wrow1[o];
        g1[c * 5 + 1] = mrow1[o];
        g1[c * 5 + 2] = srow1[o];
        g1[c * 5 + 3] = nrow1[o];
        g1[c * 5 + 4] = prow1[o];
    }

    const float inv_h = 1.0f / (float)H_;

    // ---- Token 0 tail: reduce, normalize, store (covers T1 gather latency)
    wave_reduce2(s0, q0);
    const float mu0   = s0 * inv_h;
    const float var0  = q0 * inv_h - mu0 * mu0;
    const float rstd0 = rsqrtf(var0 + LN_EPS);
    apply_store(vals0, mu0, rstd0, lane, gv, bv,
                reinterpret_cast<nfloat4*>(out + (size_t)t0 * H_));

    // ---- Token 1: consume (loads should have landed), reduce, store ----
    float vals1[12];
    float s1 = 0.0f, q1 = 0.0f;
    consume_token(g1, atau1, dtau1, aw0, ab0, dw0, db0, lane,
                  awv, abv, dwv, dbv, vals1, s1, q1);

    wave_reduce2(s1, q1);
    const float mu1   = s1 * inv_h;
    const float var1  = q1 * inv_h - mu1 * mu1;
    const float rstd1 = rsqrtf(var1 + LN_EPS);
    apply_store(vals1, mu1, rstd1, lane, gv, bv,
                reinterpret_cast<nfloat4*>(out + (size_t)t1 * H_));
}

extern "C" void kernel_launch(void* const* d_in, const int* in_sizes, int n_in,
                              void* d_out, int out_size, void* d_ws, size_t ws_size,
                              hipStream_t stream) {
    const int*   word_ids    = (const int*)  d_in[0];
    const int*   modal_ids   = (const int*)  d_in[1];
    const int*   seg_ids     = (const int*)  d_in[2];
    const int*   npi_ids     = (const int*)  d_in[3];
    const int*   posi_ids    = (const int*)  d_in[4];
    const float* age_tau     = (const float*)d_in[5];
    const float* delay_tau   = (const float*)d_in[6];
    const float* word_table  = (const float*)d_in[7];
    const float* modal_table = (const float*)d_in[8];
    const float* seg_table   = (const float*)d_in[9];
    const float* npi_table   = (const float*)d_in[10];
    const float* posi_table  = (const float*)d_in[11];
    const float* age_w       = (const float*)d_in[12];
    const float* age_b       = (const float*)d_in[13];
    const float* age_w0      = (const float*)d_in[14];
    const float* age_b0      = (const float*)d_in[15];
    const float* delay_w     = (const float*)d_in[16];
    const float* delay_b     = (const float*)d_in[17];
    const float* delay_w0    = (const float*)d_in[18];
    const float* delay_b0    = (const float*)d_in[19];
    const float* ln_gamma    = (const float*)d_in[20];
    const float* ln_beta     = (const float*)d_in[21];
    float* out = (float*)d_out;

    dim3 grid(TOKENS / 8);   // 2048 blocks, 8 tokens (4 waves x 2) each
    dim3 block(256);
    hipLaunchKernelGGL(bert_emb_kernel, grid, block, 0, stream,
                       word_ids, modal_ids, seg_ids, npi_ids, posi_ids,
                       age_tau, delay_tau,
                       word_table, modal_table, seg_table, npi_table, posi_table,
                       age_w, age_b, age_w0, age_b0,
                       delay_w, delay_b, delay_w0, delay_b0,
                       ln_gamma, ln_beta, out);
}

// Round 2
// 231.449 us; speedup vs baseline: 1.0157x; 1.0157x over previous
//
#include <hip/hip_runtime.h>
#include <cmath>

// BertEmbeddings: B=8, S=2048, H=768. fp32 in/out.
// History:
//  R0 wave-per-token, sinf:            kernel 77us (VALU 25%, VGPR 116)
//  R1 launch_bounds(256,6):            SPILL disaster (cap 85 < natural 116)
//  R3 __sinf + nt-store + (256,4):     kernel ~58us
//  R4 + LDS params + (256,5):          kernel ~54us
//  R6 chunk-per-thread (192thr/token): kernel 76us — reverted.
//  R7 readfirstlane ids + 15-gather single vmcnt group @ (256,5): ~53.5us
//     (dur 231.2 = 3x59us harness fills + kernel).
//  R8 two tokens/wave pipelined @ (256,4): kernel ~57.5us. Pipelining ~0,
//     occupancy loss -4us.  LESSON: TLP is the lever, not per-wave MLP.
// R9 (this round): R7 structure, occupancy 5->6 waves/SIMD (256,6), cap 85.
//     To fit: gathers issued 10 (chunks 0,1) + 5 (chunk 2) instead of 15,
//     peak live ~76 VGPR. Vectorized float4 LDS staging (6 loads vs 18).
//     Tail fix (h=767) only in chunk 2. Predict kernel ~47-49us.
static constexpr int B_ = 8;
static constexpr int S_ = 2048;
static constexpr int H_ = 768;            // 192 float4 chunks per row
static constexpr int TOKENS = B_ * S_;    // 16384
static constexpr float LN_EPS = 1e-12f;

typedef float nfloat4 __attribute__((ext_vector_type(4)));

__device__ __forceinline__ float rfl_f32(float x) {
    return __uint_as_float(__builtin_amdgcn_readfirstlane(__float_as_uint(x)));
}

__global__ __launch_bounds__(256, 6) void bert_emb_kernel(
    const int* __restrict__ word_ids,
    const int* __restrict__ modal_ids,
    const int* __restrict__ seg_ids,
    const int* __restrict__ npi_ids,
    const int* __restrict__ posi_ids,
    const float* __restrict__ age_tau,
    const float* __restrict__ delay_tau,
    const float* __restrict__ word_table,
    const float* __restrict__ modal_table,
    const float* __restrict__ seg_table,
    const float* __restrict__ npi_table,
    const float* __restrict__ posi_table,
    const float* __restrict__ age_w,      // [767]
    const float* __restrict__ age_b,      // [767]
    const float* __restrict__ age_w0,     // [1]
    const float* __restrict__ age_b0,     // [1]
    const float* __restrict__ delay_w,    // [767]
    const float* __restrict__ delay_b,    // [767]
    const float* __restrict__ delay_w0,   // [1]
    const float* __restrict__ delay_b0,   // [1]
    const float* __restrict__ ln_gamma,   // [768]
    const float* __restrict__ ln_beta,    // [768]
    float* __restrict__ out)
{
    __shared__ __align__(16) float s_aw[H_];
    __shared__ __align__(16) float s_ab[H_];
    __shared__ __align__(16) float s_dw[H_];
    __shared__ __align__(16) float s_db[H_];
    __shared__ __align__(16) float s_g [H_];
    __shared__ __align__(16) float s_bt[H_];

    // Vectorized cooperative staging: 192 float4 per array. The [767]-sized
    // arrays get their last float4 assembled from 3 scalars + 0 pad (no OOB).
    if (threadIdx.x < 192) {
        const int i4 = threadIdx.x;
        float4 vaw, vab, vdw, vdb;
        if (i4 < 191) {
            vaw = reinterpret_cast<const float4*>(age_w)[i4];
            vab = reinterpret_cast<const float4*>(age_b)[i4];
            vdw = reinterpret_cast<const float4*>(delay_w)[i4];
            vdb = reinterpret_cast<const float4*>(delay_b)[i4];
        } else {
            vaw = make_float4(age_w[764],   age_w[765],   age_w[766],   0.0f);
            vab = make_float4(age_b[764],   age_b[765],   age_b[766],   0.0f);
            vdw = make_float4(delay_w[764], delay_w[765], delay_w[766], 0.0f);
            vdb = make_float4(delay_b[764], delay_b[765], delay_b[766], 0.0f);
        }
        reinterpret_cast<float4*>(s_aw)[i4] = vaw;
        reinterpret_cast<float4*>(s_ab)[i4] = vab;
        reinterpret_cast<float4*>(s_dw)[i4] = vdw;
        reinterpret_cast<float4*>(s_db)[i4] = vdb;
        reinterpret_cast<float4*>(s_g )[i4] = reinterpret_cast<const float4*>(ln_gamma)[i4];
        reinterpret_cast<float4*>(s_bt)[i4] = reinterpret_cast<const float4*>(ln_beta)[i4];
    }
    __syncthreads();

    const int wave = threadIdx.x >> 6;         // 0..3
    const int lane = threadIdx.x & 63;         // 0..63
    const int token = (blockIdx.x << 2) + wave;  // grid = TOKENS/4 exactly

    // Wave-uniform scalars -> SGPRs; row bases become SGPR pairs.
    const int wid = __builtin_amdgcn_readfirstlane(word_ids[token]);
    const int mid = __builtin_amdgcn_readfirstlane(modal_ids[token]);
    const int sid = __builtin_amdgcn_readfirstlane(seg_ids[token]);
    const int nid = __builtin_amdgcn_readfirstlane(npi_ids[token]);
    const int pid = __builtin_amdgcn_readfirstlane(posi_ids[token]);
    const float atau = rfl_f32(age_tau[token]);
    const float dtau = rfl_f32(delay_tau[token]);
    const float aw0 = age_w0[0], ab0 = age_b0[0];
    const float dw0 = delay_w0[0], db0 = delay_b0[0];

    const float4* wrow = reinterpret_cast<const float4*>(word_table  + (size_t)wid * H_);
    const float4* mrow = reinterpret_cast<const float4*>(modal_table + (size_t)mid * H_);
    const float4* srow = reinterpret_cast<const float4*>(seg_table   + (size_t)sid * H_);
    const float4* nrow = reinterpret_cast<const float4*>(npi_table   + (size_t)nid * H_);
    const float4* prow = reinterpret_cast<const float4*>(posi_table  + (size_t)pid * H_);

    const float4* awv = reinterpret_cast<const float4*>(s_aw);
    const float4* abv = reinterpret_cast<const float4*>(s_ab);
    const float4* dwv = reinterpret_cast<const float4*>(s_dw);
    const float4* dbv = reinterpret_cast<const float4*>(s_db);

    float vals[12];
    float ssum = 0.0f, ssq = 0.0f;

    // Consume one chunk's 5 gathered float4s into vals/ssum/ssq.
    auto consume = [&](int c, const float4& we, const float4& me,
                       const float4& se, const float4& ne, const float4& pe) {
        const int h4 = lane + (c << 6);
        const float4 aw = awv[h4];
        const float4 ab = abv[h4];
        const float4 dw = dwv[h4];
        const float4 db = dbv[h4];

        float av0 = __sinf(atau * aw.x + ab.x);
        float av1 = __sinf(atau * aw.y + ab.y);
        float av2 = __sinf(atau * aw.z + ab.z);
        float av3 = __sinf(atau * aw.w + ab.w);
        float dv0 = __sinf(dtau * dw.x + db.x);
        float dv1 = __sinf(dtau * dw.y + db.y);
        float dv2 = __sinf(dtau * dw.z + db.z);
        float dv3 = __sinf(dtau * dw.w + db.w);
        if (c == 2 && lane == 63) {            // h = 767: linear branch of time2vec
            av3 = atau * aw0 + ab0;
            dv3 = dtau * dw0 + db0;
        }

        const float e0 = we.x + me.x + se.x + ne.x + pe.x + av0 + dv0;
        const float e1 = we.y + me.y + se.y + ne.y + pe.y + av1 + dv1;
        const float e2 = we.z + me.z + se.z + ne.z + pe.z + av2 + dv2;
        const float e3 = we.w + me.w + se.w + ne.w + pe.w + av3 + dv3;

        vals[c * 4 + 0] = e0;
        vals[c * 4 + 1] = e1;
        vals[c * 4 + 2] = e2;
        vals[c * 4 + 3] = e3;
        ssum += e0 + e1 + e2 + e3;
        ssq  += e0 * e0 + e1 * e1 + e2 * e2 + e3 * e3;
    };

    // Issue chunks 0+1 (10 loads, 40 VGPR in flight) — fits the (256,6)
    // cap of 85 alongside vals+temps; the full 15-load group (R7) did not.
    const float4 w0 = wrow[lane], w1 = wrow[lane + 64];
    const float4 m0 = mrow[lane], m1 = mrow[lane + 64];
    const float4 s0 = srow[lane], s1 = srow[lane + 64];
    const float4 n0 = nrow[lane], n1 = nrow[lane + 64];
    const float4 p0 = prow[lane], p1 = prow[lane + 64];

    consume(0, w0, m0, s0, n0, p0);

    // Issue chunk 2 while chunk 1 is consumed.
    const float4 w2 = wrow[lane + 128];
    const float4 m2 = mrow[lane + 128];
    const float4 s2 = srow[lane + 128];
    const float4 n2 = nrow[lane + 128];
    const float4 p2 = prow[lane + 128];

    consume(1, w1, m1, s1, n1, p1);
    consume(2, w2, m2, s2, n2, p2);

    // 64-lane butterfly reduction; every lane ends with the totals.
#pragma unroll
    for (int m = 32; m; m >>= 1) {
        ssum += __shfl_xor(ssum, m);
        ssq  += __shfl_xor(ssq,  m);
    }

    const float inv_h = 1.0f / (float)H_;
    const float mu = ssum * inv_h;
    const float var = ssq * inv_h - mu * mu;
    const float rstd = rsqrtf(var + LN_EPS);

    const float4* gv = reinterpret_cast<const float4*>(s_g);
    const float4* bv = reinterpret_cast<const float4*>(s_bt);
    nfloat4* orow = reinterpret_cast<nfloat4*>(out + (size_t)token * H_);

#pragma unroll
    for (int c = 0; c < 3; ++c) {
        const int h4 = lane + (c << 6);
        const float4 g  = gv[h4];
        const float4 bt = bv[h4];
        nfloat4 o;
        o.x = (vals[c * 4 + 0] - mu) * rstd * g.x + bt.x;
        o.y = (vals[c * 4 + 1] - mu) * rstd * g.y + bt.y;
        o.z = (vals[c * 4 + 2] - mu) * rstd * g.z + bt.z;
        o.w = (vals[c * 4 + 3] - mu) * rstd * g.w + bt.w;
        __builtin_nontemporal_store(o, &orow[h4]);
    }
}

extern "C" void kernel_launch(void* const* d_in, const int* in_sizes, int n_in,
                              void* d_out, int out_size, void* d_ws, size_t ws_size,
                              hipStream_t stream) {
    const int*   word_ids    = (const int*)  d_in[0];
    const int*   modal_ids   = (const int*)  d_in[1];
    const int*   seg_ids     = (const int*)  d_in[2];
    const int*   npi_ids     = (const int*)  d_in[3];
    const int*   posi_ids    = (const int*)  d_in[4];
    const float* age_tau     = (const float*)d_in[5];
    const float* delay_tau   = (const float*)d_in[6];
    const float* word_table  = (const float*)d_in[7];
    const float* modal_table = (const float*)d_in[8];
    const float* seg_table   = (const float*)d_in[9];
    const float* npi_table   = (const float*)d_in[10];
    const float* posi_table  = (const float*)d_in[11];
    const float* age_w       = (const float*)d_in[12];
    const float* age_b       = (const float*)d_in[13];
    const float* age_w0      = (const float*)d_in[14];
    const float* age_b0      = (const float*)d_in[15];
    const float* delay_w     = (const float*)d_in[16];
    const float* delay_b     = (const float*)d_in[17];
    const float* delay_w0    = (const float*)d_in[18];
    const float* delay_b0    = (const float*)d_in[19];
    const float* ln_gamma    = (const float*)d_in[20];
    const float* ln_beta     = (const float*)d_in[21];
    float* out = (float*)d_out;

    dim3 grid(TOKENS / 4);   // 4096 blocks, 4 tokens (waves) each
    dim3 block(256);
    hipLaunchKernelGGL(bert_emb_kernel, grid, block, 0, stream,
                       word_ids, modal_ids, seg_ids, npi_ids, posi_ids,
                       age_tau, delay_tau,
                       word_table, modal_table, seg_table, npi_table, posi_table,
                       age_w, age_b, age_w0, age_b0,
                       delay_w, delay_b, delay_w0, delay_b0,
                       ln_gamma, ln_beta, out);
}

// Round 3
// 229.546 us; speedup vs baseline: 1.0241x; 1.0083x over previous
//
#include <hip/hip_runtime.h>
#include <cmath>

// BertEmbeddings: B=8, S=2048, H=768. fp32 in/out.
// History:
//  R0 wave-per-token, sinf:            kernel 77us (VALU 25%, VGPR 116)
//  R1 launch_bounds(256,6):            SPILL disaster (cap 85 < natural 116)
//  R3 __sinf + nt-store + (256,4):     kernel ~58us
//  R4 + LDS params + (256,5):          kernel ~54us
//  R6 chunk-per-thread (192thr/token): kernel 76us — reverted.
//  R7 readfirstlane ids + 15-gather single vmcnt group @ (256,5): ~53.5us
//  R8 two tokens/wave pipelined @ (256,4): ~57.5us. Pipelining ~0; -1 wave = -4us.
//  R9 (256,6) + split 10+5 gathers + vec LDS staging: ~54us. +1 wave = +0.
//     LESSON: occupancy plateau at >=5 waves/SIMD; pipelining neutral.
//     Kernel sits ~3x above all single-pipe floors EXCEPT request volume:
//     245K x 1KB gather requests (251 MB) is the unreduced quantity.
// R10 (this round): WORK REMOVAL. Pre-kernel fuses modal+seg+npi into a
//     combo table [16*4*10=640][768] = 1.9 MB in d_ws (L2-resident).
//     Main kernel gathers 9 rows/token instead of 15 (-40% requests),
//     single vmcnt group (36 VGPR in flight) @ (256,5). Ids via uniform
//     token -> s_load. Predict kernel ~40us, total ~217-221.
static constexpr int B_ = 8;
static constexpr int S_ = 2048;
static constexpr int H_ = 768;            // 192 float4 chunks per row
static constexpr int TOKENS = B_ * S_;    // 16384
static constexpr float LN_EPS = 1e-12f;
static constexpr int MODAL_V = 16;
static constexpr int SEG_V   = 4;
static constexpr int NPI_V   = 10;
static constexpr int NCOMBO  = MODAL_V * SEG_V * NPI_V;   // 640

typedef float nfloat4 __attribute__((ext_vector_type(4)));

__device__ __forceinline__ float rfl_f32(float x) {
    return __uint_as_float(__builtin_amdgcn_readfirstlane(__float_as_uint(x)));
}

// ---------------------------------------------------------------------------
// Pre-kernel: combo[(mid*SEG_V+sid)*NPI_V+nid][h] = modal[mid][h]+seg[sid][h]+npi[nid][h]
// 640 blocks x 192 threads (one float4 per thread). ~0.5 MB reads, 1.9 MB writes.
// ---------------------------------------------------------------------------
__global__ __launch_bounds__(192) void combo_build_kernel(
    const float* __restrict__ modal_table,
    const float* __restrict__ seg_table,
    const float* __restrict__ npi_table,
    float* __restrict__ combo)
{
    const int row = blockIdx.x;            // 0..639
    const int nid = row % NPI_V;
    const int rem = row / NPI_V;
    const int sid = rem % SEG_V;
    const int mid = rem / SEG_V;
    const int i4  = threadIdx.x;           // 0..191
    const float4 m = reinterpret_cast<const float4*>(modal_table + (size_t)mid * H_)[i4];
    const float4 s = reinterpret_cast<const float4*>(seg_table   + (size_t)sid * H_)[i4];
    const float4 n = reinterpret_cast<const float4*>(npi_table   + (size_t)nid * H_)[i4];
    float4 o;
    o.x = m.x + s.x + n.x;
    o.y = m.y + s.y + n.y;
    o.z = m.z + s.z + n.z;
    o.w = m.w + s.w + n.w;
    reinterpret_cast<float4*>(combo + (size_t)row * H_)[i4] = o;
}

// ---------------------------------------------------------------------------
// Main kernel (combo path): 9 gathers/token in ONE vmcnt group.
// ---------------------------------------------------------------------------
__global__ __launch_bounds__(256, 5) void bert_emb_kernel_combo(
    const int* __restrict__ word_ids,
    const int* __restrict__ modal_ids,
    const int* __restrict__ seg_ids,
    const int* __restrict__ npi_ids,
    const int* __restrict__ posi_ids,
    const float* __restrict__ age_tau,
    const float* __restrict__ delay_tau,
    const float* __restrict__ word_table,
    const float* __restrict__ posi_table,
    const float* __restrict__ combo,      // [640][768]
    const float* __restrict__ age_w,      // [767]
    const float* __restrict__ age_b,      // [767]
    const float* __restrict__ age_w0,     // [1]
    const float* __restrict__ age_b0,     // [1]
    const float* __restrict__ delay_w,    // [767]
    const float* __restrict__ delay_b,    // [767]
    const float* __restrict__ delay_w0,   // [1]
    const float* __restrict__ delay_b0,   // [1]
    const float* __restrict__ ln_gamma,   // [768]
    const float* __restrict__ ln_beta,    // [768]
    float* __restrict__ out)
{
    __shared__ __align__(16) float s_aw[H_];
    __shared__ __align__(16) float s_ab[H_];
    __shared__ __align__(16) float s_dw[H_];
    __shared__ __align__(16) float s_db[H_];
    __shared__ __align__(16) float s_g [H_];
    __shared__ __align__(16) float s_bt[H_];

    if (threadIdx.x < 192) {
        const int i4 = threadIdx.x;
        float4 vaw, vab, vdw, vdb;
        if (i4 < 191) {
            vaw = reinterpret_cast<const float4*>(age_w)[i4];
            vab = reinterpret_cast<const float4*>(age_b)[i4];
            vdw = reinterpret_cast<const float4*>(delay_w)[i4];
            vdb = reinterpret_cast<const float4*>(delay_b)[i4];
        } else {
            vaw = make_float4(age_w[764],   age_w[765],   age_w[766],   0.0f);
            vab = make_float4(age_b[764],   age_b[765],   age_b[766],   0.0f);
            vdw = make_float4(delay_w[764], delay_w[765], delay_w[766], 0.0f);
            vdb = make_float4(delay_b[764], delay_b[765], delay_b[766], 0.0f);
        }
        reinterpret_cast<float4*>(s_aw)[i4] = vaw;
        reinterpret_cast<float4*>(s_ab)[i4] = vab;
        reinterpret_cast<float4*>(s_dw)[i4] = vdw;
        reinterpret_cast<float4*>(s_db)[i4] = vdb;
        reinterpret_cast<float4*>(s_g )[i4] = reinterpret_cast<const float4*>(ln_gamma)[i4];
        reinterpret_cast<float4*>(s_bt)[i4] = reinterpret_cast<const float4*>(ln_beta)[i4];
    }
    __syncthreads();

    // Uniform wave id -> token is wave-uniform in an SGPR, so the id/tau
    // loads below become scalar (s_load) fetches through the constant cache.
    const int wave = __builtin_amdgcn_readfirstlane(threadIdx.x) >> 6;  // 0..3
    const int lane = threadIdx.x & 63;
    const int token = (blockIdx.x << 2) + wave;  // grid = TOKENS/4 exactly

    const int wid = word_ids[token];
    const int cid = (modal_ids[token] * SEG_V + seg_ids[token]) * NPI_V + npi_ids[token];
    const int pid = posi_ids[token];
    const float atau = rfl_f32(age_tau[token]);
    const float dtau = rfl_f32(delay_tau[token]);
    const float aw0 = age_w0[0], ab0 = age_b0[0];
    const float dw0 = delay_w0[0], db0 = delay_b0[0];

    const float4* wrow = reinterpret_cast<const float4*>(word_table + (size_t)wid * H_);
    const float4* prow = reinterpret_cast<const float4*>(posi_table + (size_t)pid * H_);
    const float4* crow = reinterpret_cast<const float4*>(combo      + (size_t)cid * H_);

    const float4* awv = reinterpret_cast<const float4*>(s_aw);
    const float4* abv = reinterpret_cast<const float4*>(s_ab);
    const float4* dwv = reinterpret_cast<const float4*>(s_dw);
    const float4* dbv = reinterpret_cast<const float4*>(s_db);

    // Issue ALL 9 gathers: one vmcnt group, 36 VGPR in flight (fits cap 102).
    const float4 w0 = wrow[lane], w1 = wrow[lane + 64], w2 = wrow[lane + 128];
    const float4 p0 = prow[lane], p1 = prow[lane + 64], p2 = prow[lane + 128];
    const float4 c0 = crow[lane], c1 = crow[lane + 64], c2 = crow[lane + 128];

    float vals[12];
    float ssum = 0.0f, ssq = 0.0f;

    auto consume = [&](int c, const float4& we, const float4& pe, const float4& ce) {
        const int h4 = lane + (c << 6);
        const float4 aw = awv[h4];
        const float4 ab = abv[h4];
        const float4 dw = dwv[h4];
        const float4 db = dbv[h4];

        float av0 = __sinf(atau * aw.x + ab.x);
        float av1 = __sinf(atau * aw.y + ab.y);
        float av2 = __sinf(atau * aw.z + ab.z);
        float av3 = __sinf(atau * aw.w + ab.w);
        float dv0 = __sinf(dtau * dw.x + db.x);
        float dv1 = __sinf(dtau * dw.y + db.y);
        float dv2 = __sinf(dtau * dw.z + db.z);
        float dv3 = __sinf(dtau * dw.w + db.w);
        if (c == 2 && lane == 63) {            // h = 767: linear branch of time2vec
            av3 = atau * aw0 + ab0;
            dv3 = dtau * dw0 + db0;
        }

        const float e0 = we.x + pe.x + ce.x + av0 + dv0;
        const float e1 = we.y + pe.y + ce.y + av1 + dv1;
        const float e2 = we.z + pe.z + ce.z + av2 + dv2;
        const float e3 = we.w + pe.w + ce.w + av3 + dv3;

        vals[c * 4 + 0] = e0;
        vals[c * 4 + 1] = e1;
        vals[c * 4 + 2] = e2;
        vals[c * 4 + 3] = e3;
        ssum += e0 + e1 + e2 + e3;
        ssq  += e0 * e0 + e1 * e1 + e2 * e2 + e3 * e3;
    };

    consume(0, w0, p0, c0);
    consume(1, w1, p1, c1);
    consume(2, w2, p2, c2);

#pragma unroll
    for (int m = 32; m; m >>= 1) {
        ssum += __shfl_xor(ssum, m);
        ssq  += __shfl_xor(ssq,  m);
    }

    const float inv_h = 1.0f / (float)H_;
    const float mu = ssum * inv_h;
    const float var = ssq * inv_h - mu * mu;
    const float rstd = rsqrtf(var + LN_EPS);

    const float4* gv = reinterpret_cast<const float4*>(s_g);
    const float4* bv = reinterpret_cast<const float4*>(s_bt);
    nfloat4* orow = reinterpret_cast<nfloat4*>(out + (size_t)token * H_);

#pragma unroll
    for (int c = 0; c < 3; ++c) {
        const int h4 = lane + (c << 6);
        const float4 g  = gv[h4];
        const float4 bt = bv[h4];
        nfloat4 o;
        o.x = (vals[c * 4 + 0] - mu) * rstd * g.x + bt.x;
        o.y = (vals[c * 4 + 1] - mu) * rstd * g.y + bt.y;
        o.z = (vals[c * 4 + 2] - mu) * rstd * g.z + bt.z;
        o.w = (vals[c * 4 + 3] - mu) * rstd * g.w + bt.w;
        __builtin_nontemporal_store(o, &orow[h4]);
    }
}

// ---------------------------------------------------------------------------
// Fallback (R9 structure, 15 gathers) if workspace is too small for combo.
// ---------------------------------------------------------------------------
__global__ __launch_bounds__(256, 5) void bert_emb_kernel_plain(
    const int* __restrict__ word_ids,
    const int* __restrict__ modal_ids,
    const int* __restrict__ seg_ids,
    const int* __restrict__ npi_ids,
    const int* __restrict__ posi_ids,
    const float* __restrict__ age_tau,
    const float* __restrict__ delay_tau,
    const float* __restrict__ word_table,
    const float* __restrict__ modal_table,
    const float* __restrict__ seg_table,
    const float* __restrict__ npi_table,
    const float* __restrict__ posi_table,
    const float* __restrict__ age_w,
    const float* __restrict__ age_b,
    const float* __restrict__ age_w0,
    const float* __restrict__ age_b0,
    const float* __restrict__ delay_w,
    const float* __restrict__ delay_b,
    const float* __restrict__ delay_w0,
    const float* __restrict__ delay_b0,
    const float* __restrict__ ln_gamma,
    const float* __restrict__ ln_beta,
    float* __restrict__ out)
{
    __shared__ __align__(16) float s_aw[H_];
    __shared__ __align__(16) float s_ab[H_];
    __shared__ __align__(16) float s_dw[H_];
    __shared__ __align__(16) float s_db[H_];
    __shared__ __align__(16) float s_g [H_];
    __shared__ __align__(16) float s_bt[H_];

    if (threadIdx.x < 192) {
        const int i4 = threadIdx.x;
        float4 vaw, vab, vdw, vdb;
        if (i4 < 191) {
            vaw = reinterpret_cast<const float4*>(age_w)[i4];
            vab = reinterpret_cast<const float4*>(age_b)[i4];
            vdw = reinterpret_cast<const float4*>(delay_w)[i4];
            vdb = reinterpret_cast<const float4*>(delay_b)[i4];
        } else {
            vaw = make_float4(age_w[764],   age_w[765],   age_w[766],   0.0f);
            vab = make_float4(age_b[764],   age_b[765],   age_b[766],   0.0f);
            vdw = make_float4(delay_w[764], delay_w[765], delay_w[766], 0.0f);
            vdb = make_float4(delay_b[764], delay_b[765], delay_b[766], 0.0f);
        }
        reinterpret_cast<float4*>(s_aw)[i4] = vaw;
        reinterpret_cast<float4*>(s_ab)[i4] = vab;
        reinterpret_cast<float4*>(s_dw)[i4] = vdw;
        reinterpret_cast<float4*>(s_db)[i4] = vdb;
        reinterpret_cast<float4*>(s_g )[i4] = reinterpret_cast<const float4*>(ln_gamma)[i4];
        reinterpret_cast<float4*>(s_bt)[i4] = reinterpret_cast<const float4*>(ln_beta)[i4];
    }
    __syncthreads();

    const int wave = __builtin_amdgcn_readfirstlane(threadIdx.x) >> 6;
    const int lane = threadIdx.x & 63;
    const int token = (blockIdx.x << 2) + wave;

    const int wid = word_ids[token];
    const int mid = modal_ids[token];
    const int sid = seg_ids[token];
    const int nid = npi_ids[token];
    const int pid = posi_ids[token];
    const float atau = rfl_f32(age_tau[token]);
    const float dtau = rfl_f32(delay_tau[token]);
    const float aw0 = age_w0[0], ab0 = age_b0[0];
    const float dw0 = delay_w0[0], db0 = delay_b0[0];

    const float4* wrow = reinterpret_cast<const float4*>(word_table  + (size_t)wid * H_);
    const float4* mrow = reinterpret_cast<const float4*>(modal_table + (size_t)mid * H_);
    const float4* srow = reinterpret_cast<const float4*>(seg_table   + (size_t)sid * H_);
    const float4* nrow = reinterpret_cast<const float4*>(npi_table   + (size_t)nid * H_);
    const float4* prow = reinterpret_cast<const float4*>(posi_table  + (size_t)pid * H_);

    const float4* awv = reinterpret_cast<const float4*>(s_aw);
    const float4* abv = reinterpret_cast<const float4*>(s_ab);
    const float4* dwv = reinterpret_cast<const float4*>(s_dw);
    const float4* dbv = reinterpret_cast<const float4*>(s_db);

    float vals[12];
    float ssum = 0.0f, ssq = 0.0f;

    auto consume = [&](int c, const float4& we, const float4& me,
                       const float4& se, const float4& ne, const float4& pe) {
        const int h4 = lane + (c << 6);
        const float4 aw = awv[h4];
        const float4 ab = abv[h4];
        const float4 dw = dwv[h4];
        const float4 db = dbv[h4];

        float av0 = __sinf(atau * aw.x + ab.x);
        float av1 = __sinf(atau * aw.y + ab.y);
        float av2 = __sinf(atau * aw.z + ab.z);
        float av3 = __sinf(atau * aw.w + ab.w);
        float dv0 = __sinf(dtau * dw.x + db.x);
        float dv1 = __sinf(dtau * dw.y + db.y);
        float dv2 = __sinf(dtau * dw.z + db.z);
        float dv3 = __sinf(dtau * dw.w + db.w);
        if (c == 2 && lane == 63) {
            av3 = atau * aw0 + ab0;
            dv3 = dtau * dw0 + db0;
        }

        const float e0 = we.x + me.x + se.x + ne.x + pe.x + av0 + dv0;
        const float e1 = we.y + me.y + se.y + ne.y + pe.y + av1 + dv1;
        const float e2 = we.z + me.z + se.z + ne.z + pe.z + av2 + dv2;
        const float e3 = we.w + me.w + se.w + ne.w + pe.w + av3 + dv3;

        vals[c * 4 + 0] = e0;
        vals[c * 4 + 1] = e1;
        vals[c * 4 + 2] = e2;
        vals[c * 4 + 3] = e3;
        ssum += e0 + e1 + e2 + e3;
        ssq  += e0 * e0 + e1 * e1 + e2 * e2 + e3 * e3;
    };

    const float4 w0 = wrow[lane], w1 = wrow[lane + 64];
    const float4 m0 = mrow[lane], m1 = mrow[lane + 64];
    const float4 s0 = srow[lane], s1 = srow[lane + 64];
    const float4 n0 = nrow[lane], n1 = nrow[lane + 64];
    const float4 p0 = prow[lane], p1 = prow[lane + 64];

    consume(0, w0, m0, s0, n0, p0);

    const float4 w2 = wrow[lane + 128];
    const float4 m2 = mrow[lane + 128];
    const float4 s2 = srow[lane + 128];
    const float4 n2 = nrow[lane + 128];
    const float4 p2 = prow[lane + 128];

    consume(1, w1, m1, s1, n1, p1);
    consume(2, w2, m2, s2, n2, p2);

#pragma unroll
    for (int m = 32; m; m >>= 1) {
        ssum += __shfl_xor(ssum, m);
        ssq  += __shfl_xor(ssq,  m);
    }

    const float inv_h = 1.0f / (float)H_;
    const float mu = ssum * inv_h;
    const float var = ssq * inv_h - mu * mu;
    const float rstd = rsqrtf(var + LN_EPS);

    const float4* gv = reinterpret_cast<const float4*>(s_g);
    const float4* bv = reinterpret_cast<const float4*>(s_bt);
    nfloat4* orow = reinterpret_cast<nfloat4*>(out + (size_t)token * H_);

#pragma unroll
    for (int c = 0; c < 3; ++c) {
        const int h4 = lane + (c << 6);
        const float4 g  = gv[h4];
        const float4 bt = bv[h4];
        nfloat4 o;
        o.x = (vals[c * 4 + 0] - mu) * rstd * g.x + bt.x;
        o.y = (vals[c * 4 + 1] - mu) * rstd * g.y + bt.y;
        o.z = (vals[c * 4 + 2] - mu) * rstd * g.z + bt.z;
        o.w = (vals[c * 4 + 3] - mu) * rstd * g.w + bt.w;
        __builtin_nontemporal_store(o, &orow[h4]);
    }
}

extern "C" void kernel_launch(void* const* d_in, const int* in_sizes, int n_in,
                              void* d_out, int out_size, void* d_ws, size_t ws_size,
                              hipStream_t stream) {
    const int*   word_ids    = (const int*)  d_in[0];
    const int*   modal_ids   = (const int*)  d_in[1];
    const int*   seg_ids     = (const int*)  d_in[2];
    const int*   npi_ids     = (const int*)  d_in[3];
    const int*   posi_ids    = (const int*)  d_in[4];
    const float* age_tau     = (const float*)d_in[5];
    const float* delay_tau   = (const float*)d_in[6];
    const float* word_table  = (const float*)d_in[7];
    const float* modal_table = (const float*)d_in[8];
    const float* seg_table   = (const float*)d_in[9];
    const float* npi_table   = (const float*)d_in[10];
    const float* posi_table  = (const float*)d_in[11];
    const float* age_w       = (const float*)d_in[12];
    const float* age_b       = (const float*)d_in[13];
    const float* age_w0      = (const float*)d_in[14];
    const float* age_b0      = (const float*)d_in[15];
    const float* delay_w     = (const float*)d_in[16];
    const float* delay_b     = (const float*)d_in[17];
    const float* delay_w0    = (const float*)d_in[18];
    const float* delay_b0    = (const float*)d_in[19];
    const float* ln_gamma    = (const float*)d_in[20];
    const float* ln_beta     = (const float*)d_in[21];
    float* out = (float*)d_out;

    const size_t combo_bytes = (size_t)NCOMBO * H_ * sizeof(float);   // 1.9 MB

    if (d_ws != nullptr && ws_size >= combo_bytes) {
        float* combo = (float*)d_ws;
        hipLaunchKernelGGL(combo_build_kernel, dim3(NCOMBO), dim3(192), 0, stream,
                           modal_table, seg_table, npi_table, combo);
        hipLaunchKernelGGL(bert_emb_kernel_combo, dim3(TOKENS / 4), dim3(256), 0, stream,
                           word_ids, modal_ids, seg_ids, npi_ids, posi_ids,
                           age_tau, delay_tau,
                           word_table, posi_table, combo,
                           age_w, age_b, age_w0, age_b0,
                           delay_w, delay_b, delay_w0, delay_b0,
                           ln_gamma, ln_beta, out);
    } else {
        hipLaunchKernelGGL(bert_emb_kernel_plain, dim3(TOKENS / 4), dim3(256), 0, stream,
                           word_ids, modal_ids, seg_ids, npi_ids, posi_ids,
                           age_tau, delay_tau,
                           word_table, modal_table, seg_table, npi_table, posi_table,
                           age_w, age_b, age_w0, age_b0,
                           delay_w, delay_b, delay_w0, delay_b0,
                           ln_gamma, ln_beta, out);
    }
}